// Round 24
// baseline (66.970 us; speedup 1.0000x reference)
//
#include <hip/hip_runtime.h>
#include <math.h>

// Problem constants: B=32, F=2048, hw=49, A=1.
#define BB    32
#define FF    2048
#define HW    49
#define ROWS  (BB * FF)
#define DPAD  64
#define SPLIT 2
#define GHALF (FF / SPLIT)               // 1024
#define NST   (GHALF / 32)               // 32 g-tiles of 32 rows

typedef float f32x16 __attribute__((ext_vector_type(16)));
typedef _Float16 f16x8 __attribute__((ext_vector_type(8)));
typedef short s16x8 __attribute__((ext_vector_type(8)));

// exp2 via the amdgcn builtin -> single v_exp_f32, compiler-managed hazards.
__device__ inline float exp2_fast(float x) {
    return __builtin_amdgcn_exp2f(x);
}

// fp32 -> fp16 hi + fp16 lo (RNE), packed (hi<<16)|lo. Combined rel err ~2^-22.
__device__ inline unsigned f16pack(float v) {
    _Float16 h = (_Float16)v;
    _Float16 l = (_Float16)(v - (float)h);
    unsigned hb = (unsigned)__builtin_bit_cast(unsigned short, h);
    unsigned lb = (unsigned)__builtin_bit_cast(unsigned short, l);
    return (hb << 16) | lb;
}

__device__ inline void unpack8(uint4 a, uint4 b, f16x8& h, f16x8& l) {
    unsigned w[8] = {a.x, a.y, a.z, a.w, b.x, b.y, b.z, b.w};
    s16x8 hs, ls;
    #pragma unroll
    for (int i = 0; i < 8; ++i) {
        hs[i] = (short)(w[i] >> 16);
        ls[i] = (short)(w[i] & 0xFFFFu);
    }
    h = __builtin_bit_cast(f16x8, hs);
    l = __builtin_bit_cast(f16x8, ls);
}

// ---------------------------------------------------------------------------
// prep: M[j,d] = sum_e Wq[e,j] Wk[e,d] * log2(e)/7 -> Mtpk[d][j] (fp16 hi/lo)
//       u[d]   = sum_e Wv[e,d] * Wout[e]
// ---------------------------------------------------------------------------
__global__ __launch_bounds__(256) void prep_kernel(
    const float* __restrict__ Wqkv, const float* __restrict__ Wout,
    unsigned* __restrict__ Mtpk, float* __restrict__ u)
{
    __shared__ float W2[98][52];
    const int tid = threadIdx.x;
    if (blockIdx.x < 16) {
        for (int i = tid; i < 98 * 52; i += 256) {
            int e = i / 52, j = i - e * 52;
            W2[e][j] = (j < HW) ? Wqkv[e * HW + j] : 0.f;
        }
        __syncthreads();
        const int d = blockIdx.x * 4 + (tid >> 6);
        const int j = tid & 63;
        float s = 0.f;
        if (d < HW && j < HW) {
            for (int e = 0; e < HW; ++e) s = fmaf(W2[e][j], W2[49 + e][d], s);
            s *= 0.2060992915555662f;      // log2(e) / 7
        }
        Mtpk[d * 64 + j] = f16pack(s);
    } else {
        if (tid < 64) {
            float s = 0.f;
            if (tid < HW)
                for (int e = 0; e < HW; ++e)
                    s = fmaf(Wqkv[(98 + e) * HW + tid], Wout[e], s);
            u[tid] = s;
        }
    }
}

// ---------------------------------------------------------------------------
// xy: 64 rows per 128-thread block. Load x via LDS bounce, build fp16 hi/lo
// x-frags in-register, write FRAGMENT-ORDERED xf panel xf[g-tile][ks][lane][8],
// wv = x.u, then y = x.M (3-MFMA hi/lo, full precision) -> yh[row][64].
// XCD-affinity swizzle: XCD k produces b in [4k,4k+4) (what its attn reads).
// ---------------------------------------------------------------------------
__global__ __launch_bounds__(128) void xy_kernel(
    const float* __restrict__ x, const float* __restrict__ u,
    const unsigned* __restrict__ Mtpk,
    unsigned short* __restrict__ xf, unsigned short* __restrict__ yh,
    float* __restrict__ wv)
{
    __shared__ float xsh[64 * HW];
    __shared__ float ush[64];
    const int blk = (blockIdx.x & 7) * 128 + (blockIdx.x >> 3);  // affinity map
    const int tid = threadIdx.x, lane = tid & 63, wid = tid >> 6;
    const int col = lane & 31, half = lane >> 5;
    if (tid < 64) ush[tid] = u[tid];

    {
        const float* xb = x + (size_t)blk * 64 * HW;
        for (int i = tid; i < 64 * HW; i += 128) xsh[i] = xb[i];
    }
    __syncthreads();

    const int r0 = blk * 64 + wid * 32;
    const int rloc = wid * 32 + col;
    const int row = r0 + col;
    const int tile = blk * 2 + wid;     // 32-row g-tile index

    // x row -> hi/lo frags (in-register), fragment-ordered xf write, wv
    f16x8 ah[4], al[4];
    float wp = 0.f;
    #pragma unroll
    for (int ks = 0; ks < 4; ++ks) {
        s16x8 hs, ls;
        #pragma unroll
        for (int i = 0; i < 8; ++i) {
            int d = ks * 16 + half * 8 + i;
            float t = (d < HW) ? xsh[rloc * HW + d] : 0.f;
            wp = fmaf(t, ush[d], wp);
            _Float16 h = (_Float16)t;
            _Float16 l = (_Float16)(t - (float)h);
            hs[i] = __builtin_bit_cast(short, h);
            ls[i] = __builtin_bit_cast(short, l);
        }
        ah[ks] = __builtin_bit_cast(f16x8, hs);
        al[ks] = __builtin_bit_cast(f16x8, ls);
        // fragment order: [tile][ks][lane][8] -> contiguous per-wave 1KB
        *(f16x8*)(xf + ((size_t)tile * 4 + ks) * 512 + lane * 8) = ah[ks];
    }
    wp += __shfl_xor(wp, 32);
    if (half == 0) wv[row] = wp;

    // y = x.M for this wave's 32 rows (A = x-row frags, B = Mt-row frags)
    for (int dt = 0; dt < 2; ++dt) {
        f16x8 mh[4], ml[4];
        #pragma unroll
        for (int ks = 0; ks < 4; ++ks) {
            const unsigned* mp = Mtpk + (dt * 32 + col) * 64 + ks * 16 + half * 8;
            unpack8(*(const uint4*)mp, *(const uint4*)(mp + 4), mh[ks], ml[ks]);
        }
        f32x16 acc;
        #pragma unroll
        for (int i = 0; i < 16; ++i) acc[i] = 0.f;
        #pragma unroll
        for (int ks = 0; ks < 4; ++ks) {
            acc = __builtin_amdgcn_mfma_f32_32x32x16_f16(ah[ks], ml[ks], acc, 0, 0, 0);
            acc = __builtin_amdgcn_mfma_f32_32x32x16_f16(al[ks], mh[ks], acc, 0, 0, 0);
            acc = __builtin_amdgcn_mfma_f32_32x32x16_f16(ah[ks], mh[ks], acc, 0, 0, 0);
        }
        #pragma unroll
        for (int reg = 0; reg < 16; ++reg) {
            int drow = (reg & 3) + 8 * (reg >> 2) + 4 * half;
            _Float16 hv = (_Float16)acc[reg];
            yh[(size_t)(r0 + drow) * DPAD + dt * 32 + col] =
                __builtin_bit_cast(unsigned short, hv);
        }
    }
}

// ---------------------------------------------------------------------------
// attn: round-23 kernel with ONE change: the per-tile accumulator is split
// 2-way (accA: ks=0,1; accB: ks=2,3; merged with 16 v_add). The 4 MFMAs
// into one acc were a strictly serial C->D forwarding chain (~64cy each);
// depth 4 -> 2 cuts ~128cy off the ~800cy per-tile critical path. +16 VGPR
// (56 -> ~76, under the (256,4) cap of 128). Everything else identical:
// barrier-free, triple-buffer reg prefetch, fragment-ordered xf loads,
// SPLIT=2, 4 waves/block share the g-strip.
// ---------------------------------------------------------------------------
__global__ __launch_bounds__(256, 4) void attn_kernel(
    const unsigned short* __restrict__ xf, const unsigned short* __restrict__ yh,
    const float* __restrict__ wv,
    float* __restrict__ partL, float* __restrict__ partA)
{
    // XCD-chunked swizzle: 1024 blocks, 128 logical per XCD -> b in [4k,4k+4).
    const int bid = blockIdx.x;
    const int L = (bid & 7) * 128 + (bid >> 3);
    const int b   = L >> 5;
    const int r31 = L & 31;

    const int tid  = threadIdx.x;
    const int lane = tid & 63;
    const int wid  = tid >> 6;
    const int col  = lane & 31;
    const int half = lane >> 5;

    const int sp  = r31 >> 4;                 // 0..1: SAME for all block waves
    const int ftg = (r31 & 15) * 4 + wid;     // 0..63
    const int fblk0  = ftg * 32;
    const int gstart = sp * GHALF;
    const size_t bq = (size_t)b * FF;

    // hoist y-hi fragments (B operand, col = fblk0+col)
    f16x8 qhf[4];
    {
        const size_t yrow = (bq + fblk0 + col) * DPAD;
        #pragma unroll
        for (int ks = 0; ks < 4; ++ks)
            qhf[ks] = *(const f16x8*)(yh + yrow + ks * 16 + half * 8);
    }

    // fragment-ordered af base: tile t -> abase + t*2048 + ks*512 (shorts)
    const unsigned short* abase =
        xf + ((size_t)(b * (FF / 32) + sp * NST) * 4) * 512 + lane * 8;
    const float* wbase = wv + bq + gstart + 4 * half;

    float l0 = 0.f, l1 = 0.f;
    float a0 = 0.f, a1 = 0.f, a2 = 0.f, a3 = 0.f;

    f16x8 af[3][4];
    #pragma unroll
    for (int ks = 0; ks < 4; ++ks)
        af[0][ks] = *(const f16x8*)(abase + (size_t)ks * 512);
    #pragma unroll
    for (int ks = 0; ks < 4; ++ks)
        af[1][ks] = *(const f16x8*)(abase + (size_t)2048 + ks * 512);

    #pragma unroll
    for (int t = 0; t < NST; ++t) {
        // prefetch t+2 (2 tiles ahead; index (t+2)%3 is compile-time)
        if (t + 2 < NST) {
            #pragma unroll
            for (int ks = 0; ks < 4; ++ks)
                af[(t + 2) % 3][ks] =
                    *(const f16x8*)(abase + (size_t)(t + 2) * 2048 + ks * 512);
        }

        // compute tile t from af[t%3]: 2-way split accumulator halves the
        // dependent MFMA chain (4 serial -> 2 parallel pairs + vector add).
        f32x16 accA, accB;
        #pragma unroll
        for (int i = 0; i < 16; ++i) { accA[i] = 0.f; accB[i] = 0.f; }
        accA = __builtin_amdgcn_mfma_f32_32x32x16_f16(af[t % 3][0], qhf[0], accA, 0, 0, 0);
        accB = __builtin_amdgcn_mfma_f32_32x32x16_f16(af[t % 3][2], qhf[2], accB, 0, 0, 0);
        accA = __builtin_amdgcn_mfma_f32_32x32x16_f16(af[t % 3][1], qhf[1], accA, 0, 0, 0);
        accB = __builtin_amdgcn_mfma_f32_32x32x16_f16(af[t % 3][3], qhf[3], accB, 0, 0, 0);
        f32x16 acc = accA + accB;

        // D row g = (reg&3) + 8*(reg>>2) + 4*half; reg = q*4+j -> g = j+8q+4half
        const float* wpb = wbase + t * 32;
        #pragma unroll
        for (int q = 0; q < 4; ++q) {
            float4 w4 = *(const float4*)(wpb + q * 8);
            float p0 = exp2_fast(acc[q * 4 + 0]);
            float p1 = exp2_fast(acc[q * 4 + 1]);
            float p2 = exp2_fast(acc[q * 4 + 2]);
            float p3 = exp2_fast(acc[q * 4 + 3]);
            if (q & 1) l1 += ((p0 + p1) + (p2 + p3));
            else       l0 += ((p0 + p1) + (p2 + p3));
            a0 = fmaf(p0, w4.x, a0);
            a1 = fmaf(p1, w4.y, a1);
            a2 = fmaf(p2, w4.z, a2);
            a3 = fmaf(p3, w4.w, a3);
        }
    }

    float lsum = l0 + l1;
    float asum = (a0 + a1) + (a2 + a3);
    lsum += __shfl_xor(lsum, 32);
    asum += __shfl_xor(asum, 32);
    if (half == 0) {
        size_t o = ((size_t)sp * BB + b) * FF + fblk0 + col;
        partL[o] = lsum;
        partA[o] = asum;
    }
}

// ---------------------------------------------------------------------------
// bn: combine split partials, BatchNorm over batch per channel f.
// ---------------------------------------------------------------------------
__global__ __launch_bounds__(64) void bn_kernel(
    const float* __restrict__ partL, const float* __restrict__ partA,
    const float* __restrict__ gamma, const float* __restrict__ beta,
    float* __restrict__ out)
{
    const int f = blockIdx.x * 64 + threadIdx.x;
    float v[BB];
    float mean = 0.f;
    #pragma unroll
    for (int b = 0; b < BB; ++b) {
        float l = 0.f, a = 0.f;
        #pragma unroll
        for (int s = 0; s < SPLIT; ++s) {
            l += partL[((size_t)s * BB + b) * FF + f];
            a += partA[((size_t)s * BB + b) * FF + f];
        }
        v[b] = a / l;
        mean += v[b];
    }
    mean *= (1.f / BB);
    float var = 0.f;
    #pragma unroll
    for (int b = 0; b < BB; ++b) {
        float d = v[b] - mean;
        var = fmaf(d, d, var);
    }
    var *= (1.f / BB);
    const float inv = rsqrtf(var + 1e-5f);
    const float g = gamma[f], be = beta[f];
    #pragma unroll
    for (int b = 0; b < BB; ++b)
        out[((size_t)b << 11) + f] = (v[b] - mean) * inv * g + be;
}

// ---------------------------------------------------------------------------
extern "C" void kernel_launch(void* const* d_in, const int* in_sizes, int n_in,
                              void* d_out, int out_size, void* d_ws, size_t ws_size,
                              hipStream_t stream)
{
    const float* x     = (const float*)d_in[0];
    const float* Wqkv  = (const float*)d_in[1];
    const float* Wout  = (const float*)d_in[2];
    // d_in[3] = b_out: cancels exactly under BatchNorm mean subtraction.
    const float* gamma = (const float*)d_in[4];
    const float* beta  = (const float*)d_in[5];

    char* wsb = (char*)d_ws;
    const size_t PANEL = (size_t)ROWS * DPAD * sizeof(unsigned short);  // 8 MB
    unsigned short* xf = (unsigned short*)(wsb);        // fragment-ordered
    unsigned short* yh = (unsigned short*)(wsb + PANEL);
    float*          wv = (float*)(wsb + 2 * PANEL);                     // 256 KB
    unsigned*     Mtpk = (unsigned*)(wsb + 2 * PANEL + 262144);         // 16 KB
    float*           u = (float*)(wsb + 2 * PANEL + 262144 + 16384);
    float*       partL = (float*)(wsb + 2 * PANEL + 262144 + 17408);
    float*       partA = partL + (size_t)SPLIT * BB * FF;
    // total ~= 18.3 MiB

    prep_kernel<<<dim3(17), dim3(256), 0, stream>>>(Wqkv, Wout, Mtpk, u);

    xy_kernel<<<dim3(ROWS / 64), dim3(128), 0, stream>>>(
        x, u, Mtpk, xf, yh, wv);

    attn_kernel<<<dim3(BB * 16 * SPLIT), dim3(256), 0, stream>>>(
        xf, yh, wv, partL, partA);

    bn_kernel<<<dim3(FF / 64), dim3(64), 0, stream>>>(
        partL, partA, gamma, beta, (float*)d_out);
}